// Round 17
// baseline (394.902 us; speedup 1.0000x reference)
//
#include <hip/hip_runtime.h>

typedef __attribute__((ext_vector_type(8))) __bf16 bf16x8;
typedef __attribute__((ext_vector_type(4))) float f32x4;
typedef __attribute__((ext_vector_type(4))) unsigned int uint4v;

#define B_ 16
#define S_ 577
#define D_ 1408
#define H_ 16
#define HD_ 88
#define MROWS (B_*S_)   // 9232
#define N1 (3*D_)       // 4224
#define K_ D_           // 1408
#define KSTEPS 44       // 1408/32
#define VT_LD 592
// q pre-scale: (1/sqrt(88)) * log2(e)  -> QK^T emits log2-space scores
#define QSCALE 0.15379180809f

static __device__ __forceinline__ void async16(void* lds, const void* g) {
  __builtin_amdgcn_global_load_lds((const __attribute__((address_space(1))) void*)g,
                                   (__attribute__((address_space(3))) void*)lds, 16, 0, 0);
}

// bijective XCD-aware remap (m204): contiguous wgid chunk per XCD
static __device__ __forceinline__ int xcd_swizzle(int orig, int nwg) {
  int xcd = orig & 7, lid = orig >> 3;
  int q = nwg >> 3, r = nwg & 7;
  return (xcd < r ? xcd * (q + 1) : r * (q + 1) + (xcd - r) * q) + lid;
}

// ------- merged cast fp32 -> bf16 (3 arrays) + vt_g pad-column zero-fill -------
// Pad fill is REQUIRED each launch: vt_g lives in d_out, which GEMM2 overwrites
// after attention; without re-zeroing, replay 2+ would read stale fp32 bytes
// (possible NaN-as-bf16) in cols 577..591, and NaN*0 = NaN in MFMA.
__global__ void cast3_bf16_kernel(const float* __restrict__ s0, __bf16* __restrict__ d0, int n0,
                                  const float* __restrict__ s1, __bf16* __restrict__ d1, int n1,
                                  const float* __restrict__ s2, __bf16* __restrict__ d2, int n2,
                                  __bf16* __restrict__ vt, int nrow) {
  int i = blockIdx.x * blockDim.x + threadIdx.x;
  const float* s; __bf16* d; int k;
  if (i < n0) { s = s0; d = d0; k = i; }
  else if (i < n0 + n1) { s = s1; d = d1; k = i - n0; }
  else if (i < n0 + n1 + n2) { s = s2; d = d2; k = i - n0 - n1; }
  else if (i < n0 + n1 + n2 + nrow) {
    int r = i - n0 - n1 - n2;                 // b*1408 + cin
    __bf16* p = vt + (size_t)r * VT_LD + 577;
#pragma unroll
    for (int j = 0; j < 15; ++j) p[j] = (__bf16)0.f;
    return;
  } else return;
  const float4 v = ((const float4*)s)[k];
  __bf16* p = d + (size_t)k * 4;
  p[0] = (__bf16)v.x; p[1] = (__bf16)v.y; p[2] = (__bf16)v.z; p[3] = (__bf16)v.w;
}

// ---------------- GEMM1: qkv = x @ Wqkv^T + b, fused RoPE+split+permute ----------------
// 128x128 tile, BK=32, 2-phase dbuf, L2-band tile order. q pre-scaled by QSCALE.
// V section stores DIRECTLY TRANSPOSED into vt_g [bh][88][592] (transpose_v fused away).
__launch_bounds__(256, 2)
__global__ void gemm_qkv_rope(const __bf16* __restrict__ A, const __bf16* __restrict__ Bm,
                              const float* __restrict__ bias, const float* __restrict__ freqs,
                              __bf16* __restrict__ Qb, __bf16* __restrict__ Kb,
                              __bf16* __restrict__ Vt_g) {
  __shared__ __bf16 As[2][128 * 32];
  __shared__ __bf16 Bs[2][128 * 32];
  const int tid = threadIdx.x;
  const int w = tid >> 6, l = tid & 63;
  const int wgid = xcd_swizzle(blockIdx.x, 33 * 73);
  int mt, nt;
  if (wgid < 2376) { int bnd = wgid / 132, r = wgid % 132; nt = r >> 2; mt = bnd * 4 + (r & 3); }
  else             { nt = wgid - 2376; mt = 72; }
  const int m0 = mt * 128, n0 = nt * 128;
  const int wr = w & 1, wc = w >> 1;
  const int M = MROWS, K = K_;

  f32x4 acc[4][4];
#pragma unroll
  for (int m = 0; m < 4; ++m)
#pragma unroll
    for (int n = 0; n < 4; ++n) acc[m][n] = (f32x4){0.f, 0.f, 0.f, 0.f};

  int arow0 = m0 + w * 32 + (l >> 2);      if (arow0 >= M) arow0 = M - 1;
  int arow1 = m0 + w * 32 + 16 + (l >> 2); if (arow1 >= M) arow1 = M - 1;
  const __bf16* ag0 = A + (size_t)arow0 * K + (l & 3) * 8;
  const __bf16* ag1 = A + (size_t)arow1 * K + (l & 3) * 8;
  const __bf16* bg0 = Bm + (size_t)(n0 + w * 32 + (l >> 2)) * K + (l & 3) * 8;
  const __bf16* bg1 = Bm + (size_t)(n0 + w * 32 + 16 + (l >> 2)) * K + (l & 3) * 8;

  auto stage = [&](int buf, int k0) {
    async16(&As[buf][(w * 32) * 32],      ag0 + k0);
    async16(&As[buf][(w * 32 + 16) * 32], ag1 + k0);
    async16(&Bs[buf][(w * 32) * 32],      bg0 + k0);
    async16(&Bs[buf][(w * 32 + 16) * 32], bg1 + k0);
  };

  stage(0, 0);
  __syncthreads();
  for (int t = 0; t < KSTEPS; ++t) {
    const int cur = t & 1;
    if (t < KSTEPS - 1) stage(cur ^ 1, (t + 1) * 32);
    bf16x8 a[4], b[4];
#pragma unroll
    for (int m = 0; m < 4; ++m)
      a[m] = *(const bf16x8*)&As[cur][(wr * 64 + m * 16 + (l & 15)) * 32 + (l >> 4) * 8];
#pragma unroll
    for (int n = 0; n < 4; ++n)
      b[n] = *(const bf16x8*)&Bs[cur][(wc * 64 + n * 16 + (l & 15)) * 32 + (l >> 4) * 8];
#pragma unroll
    for (int m = 0; m < 4; ++m)
#pragma unroll
      for (int n = 0; n < 4; ++n)
        acc[m][n] = __builtin_amdgcn_mfma_f32_16x16x32_bf16(a[m], b[n], acc[m][n], 0, 0, 0);
    __syncthreads();
  }

  // ---- epilogue: bias + RoPE + q-prescale + head-major (q,k) / transposed (v) store ----
  const int sect = n0 / 1408;  // 0=q 1=k 2=v, uniform per block
  __bf16* dst = (sect == 0) ? Qb : (sect == 1 ? Kb : Vt_g);
  const float qs = (sect == 0) ? QSCALE : 1.f;
  int hN[4], dN[4], i2N[4], cinN[4];
  float bvN[4], sgnN[4];
#pragma unroll
  for (int n = 0; n < 4; ++n) {
    const int col = n0 + wc * 64 + n * 16 + (l & 15);
    const int cin = col - sect * 1408;
    cinN[n] = cin;
    hN[n] = cin / 88; dN[n] = cin - hN[n] * 88;
    bvN[n] = bias[col];
    i2N[n] = dN[n] & ~1;
    sgnN[n] = (dN[n] & 1) ? 1.f : -1.f;
  }
#pragma unroll
  for (int m = 0; m < 4; ++m) {
    const int rbase = m0 + wr * 64 + m * 16 + (l >> 4) * 4;
#pragma unroll
    for (int j = 0; j < 4; ++j) {
      const int r = rbase + j;
      const int s = r % 577;
      const int b = r / 577;
      const bool ok = r < MROWS;
      const float* frow = freqs + s * 88;
      __bf16* drow = dst + ((size_t)b * 16 * 577 + s) * 88;       // q/k layout
      __bf16* vrow = dst + (size_t)b * (1408 * VT_LD) + s;        // v^T layout: + cin*592
#pragma unroll
      for (int n = 0; n < 4; ++n) {
        float val = acc[m][n][j] + bvN[n];
        float outv = val;
        if (sect < 2) {
          const float2 cs = *(const float2*)&frow[i2N[n]];
          const float p = __shfl_xor(val, 1);   // all lanes execute
          outv = (val * cs.x + sgnN[n] * p * cs.y) * qs;
        }
        if (ok) {
          if (sect == 2) vrow[(size_t)cinN[n] * VT_LD] = (__bf16)outv;
          else           drow[(size_t)hN[n] * 50776 + dN[n]] = (__bf16)outv;  // 50776 = 577*88
        }
      }
    }
  }
}

// ---------------- GEMM2: out = ctx @ Wo^T + bo (fp32 out), same 2-phase loop ----------------
__launch_bounds__(256, 2)
__global__ void gemm_out_bias(const __bf16* __restrict__ A, const __bf16* __restrict__ Bm,
                              const float* __restrict__ bias, float* __restrict__ C) {
  __shared__ __bf16 As[2][128 * 32];
  __shared__ __bf16 Bs[2][128 * 32];
  const int tid = threadIdx.x;
  const int w = tid >> 6, l = tid & 63;
  const int wgid = xcd_swizzle(blockIdx.x, 11 * 73);
  int mt, nt;
  if (wgid < 792) { int bnd = wgid / 44, r = wgid % 44; nt = r >> 2; mt = bnd * 4 + (r & 3); }
  else            { nt = wgid - 792; mt = 72; }
  const int m0 = mt * 128, n0 = nt * 128;
  const int wr = w & 1, wc = w >> 1;
  const int M = MROWS, N = D_, K = K_;

  f32x4 acc[4][4];
#pragma unroll
  for (int m = 0; m < 4; ++m)
#pragma unroll
    for (int n = 0; n < 4; ++n) acc[m][n] = (f32x4){0.f, 0.f, 0.f, 0.f};

  int arow0 = m0 + w * 32 + (l >> 2);      if (arow0 >= M) arow0 = M - 1;
  int arow1 = m0 + w * 32 + 16 + (l >> 2); if (arow1 >= M) arow1 = M - 1;
  const __bf16* ag0 = A + (size_t)arow0 * K + (l & 3) * 8;
  const __bf16* ag1 = A + (size_t)arow1 * K + (l & 3) * 8;
  const __bf16* bg0 = Bm + (size_t)(n0 + w * 32 + (l >> 2)) * K + (l & 3) * 8;
  const __bf16* bg1 = Bm + (size_t)(n0 + w * 32 + 16 + (l >> 2)) * K + (l & 3) * 8;

  auto stage = [&](int buf, int k0) {
    async16(&As[buf][(w * 32) * 32],      ag0 + k0);
    async16(&As[buf][(w * 32 + 16) * 32], ag1 + k0);
    async16(&Bs[buf][(w * 32) * 32],      bg0 + k0);
    async16(&Bs[buf][(w * 32 + 16) * 32], bg1 + k0);
  };

  stage(0, 0);
  __syncthreads();
  for (int t = 0; t < KSTEPS; ++t) {
    const int cur = t & 1;
    if (t < KSTEPS - 1) stage(cur ^ 1, (t + 1) * 32);
    bf16x8 a[4], b[4];
#pragma unroll
    for (int m = 0; m < 4; ++m)
      a[m] = *(const bf16x8*)&As[cur][(wr * 64 + m * 16 + (l & 15)) * 32 + (l >> 4) * 8];
#pragma unroll
    for (int n = 0; n < 4; ++n)
      b[n] = *(const bf16x8*)&Bs[cur][(wc * 64 + n * 16 + (l & 15)) * 32 + (l >> 4) * 8];
#pragma unroll
    for (int m = 0; m < 4; ++m)
#pragma unroll
      for (int n = 0; n < 4; ++n)
        acc[m][n] = __builtin_amdgcn_mfma_f32_16x16x32_bf16(a[m], b[n], acc[m][n], 0, 0, 0);
    __syncthreads();
  }

#pragma unroll
  for (int n = 0; n < 4; ++n) {
    int col = n0 + wc * 64 + n * 16 + (l & 15);
    float bv = bias[col];
#pragma unroll
    for (int m = 0; m < 4; ++m) {
      int rbase = m0 + wr * 64 + m * 16 + (l >> 4) * 4;
#pragma unroll
      for (int j = 0; j < 4; ++j) {
        int r = rbase + j;
        if (r < MROWS) C[(size_t)r * N + col] = acc[m][n][j] + bv;
      }
    }
  }
}

// ---------------- flash attention: block = (bh, 128 q-rows), 4 waves x 32 rows ----------------
// gload_lds staging; scores in log2-space; defer-max THR=8. (R11/R15 version — best measured.)
__launch_bounds__(256, 3)
__global__ void attn_kernel(const __bf16* __restrict__ Q, const __bf16* __restrict__ K,
                            const __bf16* __restrict__ Vt_gp, __bf16* __restrict__ ctx) {
  __shared__ __bf16 lds[26368];
  const int tid = threadIdx.x;
  const int w = tid >> 6, l = tid & 63;
  const int bh = blockIdx.x;
  const int q0 = blockIdx.y * 128;
  const __bf16* qp = Q + (size_t)bh * 577 * 88;
  const __bf16* kp = K + (size_t)bh * 577 * 88;
  const __bf16* vtp = Vt_gp + (size_t)bh * 88 * VT_LD;
  __bf16* Qs = lds;             // [128][96]
  __bf16* Ks = lds + 12288;     // [64][88]
  __bf16* Vt = lds + 17920;     // [96][88]
  __bf16* Pw = lds + w * 2304;  // per-wave P [32][72]

  for (int i = tid; i < 128 * 11; i += 256) {
    int r = i / 11, off = i % 11;
    int gr = q0 + r; if (gr > 576) gr = 576;
    *(uint4v*)&Qs[r * 96 + off * 8] = *(const uint4v*)(qp + (size_t)gr * 88 + off * 8);
  }
  if (tid < 128) { uint4v z = 0; *(uint4v*)&Qs[tid * 96 + 88] = z; }
  __syncthreads();

  bf16x8 qf[2][3];
#pragma unroll
  for (int mg = 0; mg < 2; ++mg)
#pragma unroll
    for (int kk = 0; kk < 3; ++kk)
      qf[mg][kk] = *(const bf16x8*)&Qs[(w * 32 + mg * 16 + (l & 15)) * 96 + kk * 32 + (l >> 4) * 8];

  int preA[7], preB[7];
#pragma unroll
  for (int kch = 0; kch < 7; ++kch) {
    int c = w + 4 * kch;
    int a = 0, b2 = 0;
    if (c < 11) a = c * 512 + l * 8;
    else if (c < 27) { int e = (c - 11) * 512 + l * 8; a = (e / 88) * VT_LD; b2 = e % 88; }
    preA[kch] = a; preB[kch] = b2;
  }

  f32x4 oacc[2][6];
#pragma unroll
  for (int mg = 0; mg < 2; ++mg)
#pragma unroll
    for (int dn = 0; dn < 6; ++dn) oacc[mg][dn] = (f32x4){0.f, 0.f, 0.f, 0.f};
  f32x4 mrun[2], lrun[2];
  mrun[0] = -1e30f; mrun[1] = -1e30f;
  lrun[0] = 0.f; lrun[1] = 0.f;

  for (int t = 0; t < 10; ++t) {
    const int s0 = t * 64;
    if (t) __syncthreads();
#pragma unroll
    for (int kch = 0; kch < 7; ++kch) {
      int c = w + 4 * kch;
      if (c < 11) {
        async16(Ks + c * 512, kp + (size_t)s0 * 88 + preA[kch]);
      } else if (c < 27) {
        int g = s0 + preB[kch]; if (g > 584) g = 584;   // stays in-row; pad cols zeroed by cast3
        async16(Vt + (c - 11) * 512, vtp + preA[kch] + g);
      }
    }
    __syncthreads();

    f32x4 sc[2][4];
#pragma unroll
    for (int mg = 0; mg < 2; ++mg)
#pragma unroll
      for (int n = 0; n < 4; ++n) sc[mg][n] = (f32x4){0.f, 0.f, 0.f, 0.f};
#pragma unroll
    for (int n = 0; n < 4; ++n) {
#pragma unroll
      for (int kk = 0; kk < 3; ++kk) {
        bf16x8 kf = *(const bf16x8*)&Ks[(n * 16 + (l & 15)) * 88 + kk * 32 + (l >> 4) * 8];
        sc[0][n] = __builtin_amdgcn_mfma_f32_16x16x32_bf16(qf[0][kk], kf, sc[0][n], 0, 0, 0);
        sc[1][n] = __builtin_amdgcn_mfma_f32_16x16x32_bf16(qf[1][kk], kf, sc[1][n], 0, 0, 0);
      }
    }

    // mask invalid cols (scores already log2-scaled)
    f32x4 tmax[2];
    tmax[0] = -1e30f; tmax[1] = -1e30f;
#pragma unroll
    for (int n = 0; n < 4; ++n) {
      const int kc = s0 + n * 16 + (l & 15);
      const bool valid = kc < 577;
#pragma unroll
      for (int mg = 0; mg < 2; ++mg)
#pragma unroll
        for (int j = 0; j < 4; ++j) {
          float v = valid ? sc[mg][n][j] : -1e30f;
          sc[mg][n][j] = v;
          tmax[mg][j] = fmaxf(tmax[mg][j], v);
        }
    }
#pragma unroll
    for (int o = 1; o < 16; o <<= 1)
#pragma unroll
      for (int mg = 0; mg < 2; ++mg)
#pragma unroll
        for (int j = 0; j < 4; ++j)
          tmax[mg][j] = fmaxf(tmax[mg][j], __shfl_xor(tmax[mg][j], o));

    // defer-max: rescale only when some row's max grew by > 8 (log2 space)
    bool need = false;
#pragma unroll
    for (int mg = 0; mg < 2; ++mg)
#pragma unroll
      for (int j = 0; j < 4; ++j)
        need = need || (tmax[mg][j] > mrun[mg][j] + 8.f);
    if (__any(need)) {
#pragma unroll
      for (int mg = 0; mg < 2; ++mg)
#pragma unroll
        for (int j = 0; j < 4; ++j) {
          float mo = mrun[mg][j];
          float mn = fmaxf(mo, tmax[mg][j]);
          float sf = exp2f(mo - mn);
          mrun[mg][j] = mn;
          lrun[mg][j] *= sf;
#pragma unroll
          for (int dn = 0; dn < 6; ++dn) oacc[mg][dn][j] *= sf;
        }
    }
#pragma unroll
    for (int mg = 0; mg < 2; ++mg)
#pragma unroll
      for (int n = 0; n < 4; ++n)
#pragma unroll
        for (int j = 0; j < 4; ++j) {
          float p = exp2f(sc[mg][n][j] - mrun[mg][j]);   // bounded by 2^8
          lrun[mg][j] += p;
          Pw[(mg * 16 + (l >> 4) * 4 + j) * 72 + n * 16 + (l & 15)] = (__bf16)p;
        }

#pragma unroll
    for (int ks = 0; ks < 2; ++ks) {
      bf16x8 pa0 = *(const bf16x8*)&Pw[((l & 15)) * 72 + ks * 32 + (l >> 4) * 8];
      bf16x8 pa1 = *(const bf16x8*)&Pw[(16 + (l & 15)) * 72 + ks * 32 + (l >> 4) * 8];
#pragma unroll
      for (int dn = 0; dn < 6; ++dn) {
        bf16x8 vb = *(const bf16x8*)&Vt[(dn * 16 + (l & 15)) * 88 + ks * 32 + (l >> 4) * 8];
        oacc[0][dn] = __builtin_amdgcn_mfma_f32_16x16x32_bf16(pa0, vb, oacc[0][dn], 0, 0, 0);
        oacc[1][dn] = __builtin_amdgcn_mfma_f32_16x16x32_bf16(pa1, vb, oacc[1][dn], 0, 0, 0);
      }
    }
  }

#pragma unroll
  for (int o = 1; o < 16; o <<= 1)
#pragma unroll
    for (int mg = 0; mg < 2; ++mg)
#pragma unroll
      for (int j = 0; j < 4; ++j)
        lrun[mg][j] += __shfl_xor(lrun[mg][j], o);

  const int b = bh >> 4, h = bh & 15;
#pragma unroll
  for (int mg = 0; mg < 2; ++mg) {
    float inv[4];
#pragma unroll
    for (int j = 0; j < 4; ++j) inv[j] = 1.f / lrun[mg][j];
    const int sqb = q0 + w * 32 + mg * 16 + (l >> 4) * 4;
#pragma unroll
    for (int dn = 0; dn < 6; ++dn) {
      const int d = dn * 16 + (l & 15);
      if (d >= 88) continue;
#pragma unroll
      for (int j = 0; j < 4; ++j) {
        const int sq = sqb + j;
        if (sq < 577)
          ctx[((size_t)(b * 577 + sq)) * 1408 + h * 88 + d] = (__bf16)(oacc[mg][dn][j] * inv[j]);
      }
    }
  }
}

extern "C" void kernel_launch(void* const* d_in, const int* in_sizes, int n_in,
                              void* d_out, int out_size, void* d_ws, size_t ws_size,
                              hipStream_t stream) {
  const float* hs    = (const float*)d_in[0];
  const float* freqs = (const float*)d_in[1];
  const float* wqkv  = (const float*)d_in[2];
  const float* bqkv  = (const float*)d_in[3];
  const float* wo    = (const float*)d_in[4];
  const float* bo    = (const float*)d_in[5];
  float* out = (float*)d_out;

  char* ws = (char*)d_ws;
  size_t off = 0;
  auto alloc = [&](size_t bytes) {
    void* p = ws + off;
    off += (bytes + 255) & ~(size_t)255;
    return p;
  };
  __bf16* x_bf    = (__bf16*)alloc((size_t)MROWS * K_ * 2);
  __bf16* ctx_bf  = x_bf;  // aliased: x dead after GEMM1
  __bf16* wqkv_bf = (__bf16*)alloc((size_t)N1 * K_ * 2);
  __bf16* wo_bf   = (__bf16*)alloc((size_t)D_ * K_ * 2);
  __bf16* q_bf    = (__bf16*)alloc((size_t)MROWS * D_ * 2);
  __bf16* k_bf    = (__bf16*)alloc((size_t)MROWS * D_ * 2);
  (void)alloc(64 * 1024);  // guard: attn's benign K-row overrun (tile 9) stays in owned ws
  __bf16* vt_g    = (__bf16*)d_out;  // V^T written by GEMM1; GEMM2 overwrites d_out later

  const int n0 = MROWS * K_ / 4, n1 = N1 * K_ / 4, n2 = D_ * K_ / 4;
  const int nrow = 16 * 1408;  // vt_g pad rows to zero-fill (cols 577..591)
  cast3_bf16_kernel<<<(n0 + n1 + n2 + nrow + 255) / 256, 256, 0, stream>>>(
      hs, x_bf, n0, wqkv, wqkv_bf, n1, wo, wo_bf, n2, vt_g, nrow);

  gemm_qkv_rope<<<33 * 73, 256, 0, stream>>>(x_bf, wqkv_bf, bqkv, freqs, q_bf, k_bf, vt_g);

  attn_kernel<<<dim3(256, 5), 256, 0, stream>>>(q_bf, k_bf, vt_g, ctx_bf);

  gemm_out_bias<<<11 * 73, 256, 0, stream>>>(ctx_bf, wo_bf, bo, out);
}

// Round 18
// 387.001 us; speedup vs baseline: 1.0204x; 1.0204x over previous
//
#include <hip/hip_runtime.h>

typedef __attribute__((ext_vector_type(8))) __bf16 bf16x8;
typedef __attribute__((ext_vector_type(4))) float f32x4;
typedef __attribute__((ext_vector_type(4))) unsigned int uint4v;

#define B_ 16
#define S_ 577
#define D_ 1408
#define H_ 16
#define HD_ 88
#define MROWS (B_*S_)   // 9232
#define N1 (3*D_)       // 4224
#define K_ D_           // 1408
#define KSTEPS 44       // 1408/32
#define VT_LD 592
// q pre-scale: (1/sqrt(88)) * log2(e)  -> QK^T emits log2-space scores
#define QSCALE 0.15379180809f

static __device__ __forceinline__ void async16(void* lds, const void* g) {
  __builtin_amdgcn_global_load_lds((const __attribute__((address_space(1))) void*)g,
                                   (__attribute__((address_space(3))) void*)lds, 16, 0, 0);
}

// bijective XCD-aware remap (m204): contiguous wgid chunk per XCD
static __device__ __forceinline__ int xcd_swizzle(int orig, int nwg) {
  int xcd = orig & 7, lid = orig >> 3;
  int q = nwg >> 3, r = nwg & 7;
  return (xcd < r ? xcd * (q + 1) : r * (q + 1) + (xcd - r) * q) + lid;
}

// ---------------- merged cast fp32 -> bf16 (3 arrays, one launch) ----------------
__global__ void cast3_bf16_kernel(const float* __restrict__ s0, __bf16* __restrict__ d0, int n0,
                                  const float* __restrict__ s1, __bf16* __restrict__ d1, int n1,
                                  const float* __restrict__ s2, __bf16* __restrict__ d2, int n2) {
  int i = blockIdx.x * blockDim.x + threadIdx.x;
  const float* s; __bf16* d; int k;
  if (i < n0) { s = s0; d = d0; k = i; }
  else if (i < n0 + n1) { s = s1; d = d1; k = i - n0; }
  else if (i < n0 + n1 + n2) { s = s2; d = d2; k = i - n0 - n1; }
  else return;
  const float4 v = ((const float4*)s)[k];
  __bf16* p = d + (size_t)k * 4;
  p[0] = (__bf16)v.x; p[1] = (__bf16)v.y; p[2] = (__bf16)v.z; p[3] = (__bf16)v.w;
}

// ---------------- GEMM1: qkv = x @ Wqkv^T + b, fused RoPE+split+permute ----------------
// 128x128 tile, BK=32, 2-phase dbuf, L2-band tile order. q pre-scaled by QSCALE.
__launch_bounds__(256, 2)
__global__ void gemm_qkv_rope(const __bf16* __restrict__ A, const __bf16* __restrict__ Bm,
                              const float* __restrict__ bias, const float* __restrict__ freqs,
                              __bf16* __restrict__ Qb, __bf16* __restrict__ Kb,
                              __bf16* __restrict__ Vb) {
  __shared__ __bf16 As[2][128 * 32];
  __shared__ __bf16 Bs[2][128 * 32];
  const int tid = threadIdx.x;
  const int w = tid >> 6, l = tid & 63;
  const int wgid = xcd_swizzle(blockIdx.x, 33 * 73);
  int mt, nt;
  if (wgid < 2376) { int bnd = wgid / 132, r = wgid % 132; nt = r >> 2; mt = bnd * 4 + (r & 3); }
  else             { nt = wgid - 2376; mt = 72; }
  const int m0 = mt * 128, n0 = nt * 128;
  const int wr = w & 1, wc = w >> 1;
  const int M = MROWS, K = K_;

  f32x4 acc[4][4];
#pragma unroll
  for (int m = 0; m < 4; ++m)
#pragma unroll
    for (int n = 0; n < 4; ++n) acc[m][n] = (f32x4){0.f, 0.f, 0.f, 0.f};

  int arow0 = m0 + w * 32 + (l >> 2);      if (arow0 >= M) arow0 = M - 1;
  int arow1 = m0 + w * 32 + 16 + (l >> 2); if (arow1 >= M) arow1 = M - 1;
  const __bf16* ag0 = A + (size_t)arow0 * K + (l & 3) * 8;
  const __bf16* ag1 = A + (size_t)arow1 * K + (l & 3) * 8;
  const __bf16* bg0 = Bm + (size_t)(n0 + w * 32 + (l >> 2)) * K + (l & 3) * 8;
  const __bf16* bg1 = Bm + (size_t)(n0 + w * 32 + 16 + (l >> 2)) * K + (l & 3) * 8;

  auto stage = [&](int buf, int k0) {
    async16(&As[buf][(w * 32) * 32],      ag0 + k0);
    async16(&As[buf][(w * 32 + 16) * 32], ag1 + k0);
    async16(&Bs[buf][(w * 32) * 32],      bg0 + k0);
    async16(&Bs[buf][(w * 32 + 16) * 32], bg1 + k0);
  };

  stage(0, 0);
  __syncthreads();
  for (int t = 0; t < KSTEPS; ++t) {
    const int cur = t & 1;
    if (t < KSTEPS - 1) stage(cur ^ 1, (t + 1) * 32);
    bf16x8 a[4], b[4];
#pragma unroll
    for (int m = 0; m < 4; ++m)
      a[m] = *(const bf16x8*)&As[cur][(wr * 64 + m * 16 + (l & 15)) * 32 + (l >> 4) * 8];
#pragma unroll
    for (int n = 0; n < 4; ++n)
      b[n] = *(const bf16x8*)&Bs[cur][(wc * 64 + n * 16 + (l & 15)) * 32 + (l >> 4) * 8];
#pragma unroll
    for (int m = 0; m < 4; ++m)
#pragma unroll
      for (int n = 0; n < 4; ++n)
        acc[m][n] = __builtin_amdgcn_mfma_f32_16x16x32_bf16(a[m], b[n], acc[m][n], 0, 0, 0);
    __syncthreads();
  }

  // ---- epilogue: bias + RoPE + q-prescale + head-major store ----
  const int sect = n0 / 1408;  // 0=q 1=k 2=v, uniform per block
  __bf16* dst = (sect == 0) ? Qb : (sect == 1 ? Kb : Vb);
  const float qs = (sect == 0) ? QSCALE : 1.f;
  int hN[4], dN[4], i2N[4];
  float bvN[4], sgnN[4];
#pragma unroll
  for (int n = 0; n < 4; ++n) {
    const int col = n0 + wc * 64 + n * 16 + (l & 15);
    const int cin = col - sect * 1408;
    hN[n] = cin / 88; dN[n] = cin - hN[n] * 88;
    bvN[n] = bias[col];
    i2N[n] = dN[n] & ~1;
    sgnN[n] = (dN[n] & 1) ? 1.f : -1.f;
  }
#pragma unroll
  for (int m = 0; m < 4; ++m) {
    const int rbase = m0 + wr * 64 + m * 16 + (l >> 4) * 4;
#pragma unroll
    for (int j = 0; j < 4; ++j) {
      const int r = rbase + j;
      const int s = r % 577;
      const int b = r / 577;
      const bool ok = r < MROWS;
      const float* frow = freqs + s * 88;
      __bf16* drow = dst + ((size_t)b * 16 * 577 + s) * 88;
#pragma unroll
      for (int n = 0; n < 4; ++n) {
        float val = acc[m][n][j] + bvN[n];
        float outv = val;
        if (sect < 2) {
          const float2 cs = *(const float2*)&frow[i2N[n]];
          const float p = __shfl_xor(val, 1);   // all lanes execute
          outv = (val * cs.x + sgnN[n] * p * cs.y) * qs;
        }
        if (ok) drow[(size_t)hN[n] * 50776 + dN[n]] = (__bf16)outv;  // 50776 = 577*88
      }
    }
  }
}

// ---------------- GEMM2: out = ctx @ Wo^T + bo (fp32 out), same 2-phase loop ----------------
__launch_bounds__(256, 2)
__global__ void gemm_out_bias(const __bf16* __restrict__ A, const __bf16* __restrict__ Bm,
                              const float* __restrict__ bias, float* __restrict__ C) {
  __shared__ __bf16 As[2][128 * 32];
  __shared__ __bf16 Bs[2][128 * 32];
  const int tid = threadIdx.x;
  const int w = tid >> 6, l = tid & 63;
  const int wgid = xcd_swizzle(blockIdx.x, 11 * 73);
  int mt, nt;
  if (wgid < 792) { int bnd = wgid / 44, r = wgid % 44; nt = r >> 2; mt = bnd * 4 + (r & 3); }
  else            { nt = wgid - 792; mt = 72; }
  const int m0 = mt * 128, n0 = nt * 128;
  const int wr = w & 1, wc = w >> 1;
  const int M = MROWS, N = D_, K = K_;

  f32x4 acc[4][4];
#pragma unroll
  for (int m = 0; m < 4; ++m)
#pragma unroll
    for (int n = 0; n < 4; ++n) acc[m][n] = (f32x4){0.f, 0.f, 0.f, 0.f};

  int arow0 = m0 + w * 32 + (l >> 2);      if (arow0 >= M) arow0 = M - 1;
  int arow1 = m0 + w * 32 + 16 + (l >> 2); if (arow1 >= M) arow1 = M - 1;
  const __bf16* ag0 = A + (size_t)arow0 * K + (l & 3) * 8;
  const __bf16* ag1 = A + (size_t)arow1 * K + (l & 3) * 8;
  const __bf16* bg0 = Bm + (size_t)(n0 + w * 32 + (l >> 2)) * K + (l & 3) * 8;
  const __bf16* bg1 = Bm + (size_t)(n0 + w * 32 + 16 + (l >> 2)) * K + (l & 3) * 8;

  auto stage = [&](int buf, int k0) {
    async16(&As[buf][(w * 32) * 32],      ag0 + k0);
    async16(&As[buf][(w * 32 + 16) * 32], ag1 + k0);
    async16(&Bs[buf][(w * 32) * 32],      bg0 + k0);
    async16(&Bs[buf][(w * 32 + 16) * 32], bg1 + k0);
  };

  stage(0, 0);
  __syncthreads();
  for (int t = 0; t < KSTEPS; ++t) {
    const int cur = t & 1;
    if (t < KSTEPS - 1) stage(cur ^ 1, (t + 1) * 32);
    bf16x8 a[4], b[4];
#pragma unroll
    for (int m = 0; m < 4; ++m)
      a[m] = *(const bf16x8*)&As[cur][(wr * 64 + m * 16 + (l & 15)) * 32 + (l >> 4) * 8];
#pragma unroll
    for (int n = 0; n < 4; ++n)
      b[n] = *(const bf16x8*)&Bs[cur][(wc * 64 + n * 16 + (l & 15)) * 32 + (l >> 4) * 8];
#pragma unroll
    for (int m = 0; m < 4; ++m)
#pragma unroll
      for (int n = 0; n < 4; ++n)
        acc[m][n] = __builtin_amdgcn_mfma_f32_16x16x32_bf16(a[m], b[n], acc[m][n], 0, 0, 0);
    __syncthreads();
  }

#pragma unroll
  for (int n = 0; n < 4; ++n) {
    int col = n0 + wc * 64 + n * 16 + (l & 15);
    float bv = bias[col];
#pragma unroll
    for (int m = 0; m < 4; ++m) {
      int rbase = m0 + wr * 64 + m * 16 + (l >> 4) * 4;
#pragma unroll
      for (int j = 0; j < 4; ++j) {
        int r = rbase + j;
        if (r < MROWS) C[(size_t)r * N + col] = acc[m][n][j] + bv;
      }
    }
  }
}

// ---------------- V transpose: v_bf [bh][577][88] -> Vt_g [bh][88][592] ----------------
__global__ void transpose_v(const __bf16* __restrict__ V, __bf16* __restrict__ Vt_g) {
  __shared__ __bf16 Ls[64 * 104];
  const int bh = blockIdx.x, t = blockIdx.y, s0 = t * 64;
  const int tid = threadIdx.x;
  const __bf16* vp = V + (size_t)bh * 577 * 88;
  for (int i = tid; i < 64 * 11; i += 256) {
    int r = i / 11, off = i % 11;
    int gs = s0 + r; if (gs > 576) gs = 576;
    *(uint4v*)&Ls[r * 104 + off * 8] = *(const uint4v*)(vp + (size_t)gs * 88 + off * 8);
  }
  __syncthreads();
  for (int i = tid; i < 88 * 8; i += 256) {
    int d = i / 8, so = (i % 8) * 8;
    int sc_ = s0 + so;
    if (sc_ < VT_LD) {
      __bf16 tmp[8];
#pragma unroll
      for (int j = 0; j < 8; ++j) tmp[j] = Ls[(so + j) * 104 + d];
      *(uint4v*)&Vt_g[((size_t)bh * 88 + d) * VT_LD + sc_] = *(uint4v*)tmp;
    }
  }
}

// ---------------- flash attention: block = (bh, 128 q-rows), 4 waves x 32 rows ----------------
// gload_lds staging; scores in log2-space; defer-max THR=8. (R11/R15 version — best measured.)
__launch_bounds__(256, 3)
__global__ void attn_kernel(const __bf16* __restrict__ Q, const __bf16* __restrict__ K,
                            const __bf16* __restrict__ Vt_gp, __bf16* __restrict__ ctx) {
  __shared__ __bf16 lds[26368];
  const int tid = threadIdx.x;
  const int w = tid >> 6, l = tid & 63;
  const int bh = blockIdx.x;
  const int q0 = blockIdx.y * 128;
  const __bf16* qp = Q + (size_t)bh * 577 * 88;
  const __bf16* kp = K + (size_t)bh * 577 * 88;
  const __bf16* vtp = Vt_gp + (size_t)bh * 88 * VT_LD;
  __bf16* Qs = lds;             // [128][96]
  __bf16* Ks = lds + 12288;     // [64][88]
  __bf16* Vt = lds + 17920;     // [96][88]
  __bf16* Pw = lds + w * 2304;  // per-wave P [32][72]

  for (int i = tid; i < 128 * 11; i += 256) {
    int r = i / 11, off = i % 11;
    int gr = q0 + r; if (gr > 576) gr = 576;
    *(uint4v*)&Qs[r * 96 + off * 8] = *(const uint4v*)(qp + (size_t)gr * 88 + off * 8);
  }
  if (tid < 128) { uint4v z = 0; *(uint4v*)&Qs[tid * 96 + 88] = z; }
  __syncthreads();

  bf16x8 qf[2][3];
#pragma unroll
  for (int mg = 0; mg < 2; ++mg)
#pragma unroll
    for (int kk = 0; kk < 3; ++kk)
      qf[mg][kk] = *(const bf16x8*)&Qs[(w * 32 + mg * 16 + (l & 15)) * 96 + kk * 32 + (l >> 4) * 8];

  int preA[7], preB[7];
#pragma unroll
  for (int kch = 0; kch < 7; ++kch) {
    int c = w + 4 * kch;
    int a = 0, b2 = 0;
    if (c < 11) a = c * 512 + l * 8;
    else if (c < 27) { int e = (c - 11) * 512 + l * 8; a = (e / 88) * VT_LD; b2 = e % 88; }
    preA[kch] = a; preB[kch] = b2;
  }

  f32x4 oacc[2][6];
#pragma unroll
  for (int mg = 0; mg < 2; ++mg)
#pragma unroll
    for (int dn = 0; dn < 6; ++dn) oacc[mg][dn] = (f32x4){0.f, 0.f, 0.f, 0.f};
  f32x4 mrun[2], lrun[2];
  mrun[0] = -1e30f; mrun[1] = -1e30f;
  lrun[0] = 0.f; lrun[1] = 0.f;

  for (int t = 0; t < 10; ++t) {
    const int s0 = t * 64;
    if (t) __syncthreads();
#pragma unroll
    for (int kch = 0; kch < 7; ++kch) {
      int c = w + 4 * kch;
      if (c < 11) {
        async16(Ks + c * 512, kp + (size_t)s0 * 88 + preA[kch]);
      } else if (c < 27) {
        int g = s0 + preB[kch]; if (g > 584) g = 584;
        async16(Vt + (c - 11) * 512, vtp + preA[kch] + g);
      }
    }
    __syncthreads();

    f32x4 sc[2][4];
#pragma unroll
    for (int mg = 0; mg < 2; ++mg)
#pragma unroll
      for (int n = 0; n < 4; ++n) sc[mg][n] = (f32x4){0.f, 0.f, 0.f, 0.f};
#pragma unroll
    for (int n = 0; n < 4; ++n) {
#pragma unroll
      for (int kk = 0; kk < 3; ++kk) {
        bf16x8 kf = *(const bf16x8*)&Ks[(n * 16 + (l & 15)) * 88 + kk * 32 + (l >> 4) * 8];
        sc[0][n] = __builtin_amdgcn_mfma_f32_16x16x32_bf16(qf[0][kk], kf, sc[0][n], 0, 0, 0);
        sc[1][n] = __builtin_amdgcn_mfma_f32_16x16x32_bf16(qf[1][kk], kf, sc[1][n], 0, 0, 0);
      }
    }

    // mask invalid cols (scores already log2-scaled)
    f32x4 tmax[2];
    tmax[0] = -1e30f; tmax[1] = -1e30f;
#pragma unroll
    for (int n = 0; n < 4; ++n) {
      const int kc = s0 + n * 16 + (l & 15);
      const bool valid = kc < 577;
#pragma unroll
      for (int mg = 0; mg < 2; ++mg)
#pragma unroll
        for (int j = 0; j < 4; ++j) {
          float v = valid ? sc[mg][n][j] : -1e30f;
          sc[mg][n][j] = v;
          tmax[mg][j] = fmaxf(tmax[mg][j], v);
        }
    }
#pragma unroll
    for (int o = 1; o < 16; o <<= 1)
#pragma unroll
      for (int mg = 0; mg < 2; ++mg)
#pragma unroll
        for (int j = 0; j < 4; ++j)
          tmax[mg][j] = fmaxf(tmax[mg][j], __shfl_xor(tmax[mg][j], o));

    // defer-max: rescale only when some row's max grew by > 8 (log2 space)
    bool need = false;
#pragma unroll
    for (int mg = 0; mg < 2; ++mg)
#pragma unroll
      for (int j = 0; j < 4; ++j)
        need = need || (tmax[mg][j] > mrun[mg][j] + 8.f);
    if (__any(need)) {
#pragma unroll
      for (int mg = 0; mg < 2; ++mg)
#pragma unroll
        for (int j = 0; j < 4; ++j) {
          float mo = mrun[mg][j];
          float mn = fmaxf(mo, tmax[mg][j]);
          float sf = exp2f(mo - mn);
          mrun[mg][j] = mn;
          lrun[mg][j] *= sf;
#pragma unroll
          for (int dn = 0; dn < 6; ++dn) oacc[mg][dn][j] *= sf;
        }
    }
#pragma unroll
    for (int mg = 0; mg < 2; ++mg)
#pragma unroll
      for (int n = 0; n < 4; ++n)
#pragma unroll
        for (int j = 0; j < 4; ++j) {
          float p = exp2f(sc[mg][n][j] - mrun[mg][j]);   // bounded by 2^8
          lrun[mg][j] += p;
          Pw[(mg * 16 + (l >> 4) * 4 + j) * 72 + n * 16 + (l & 15)] = (__bf16)p;
        }

#pragma unroll
    for (int ks = 0; ks < 2; ++ks) {
      bf16x8 pa0 = *(const bf16x8*)&Pw[((l & 15)) * 72 + ks * 32 + (l >> 4) * 8];
      bf16x8 pa1 = *(const bf16x8*)&Pw[(16 + (l & 15)) * 72 + ks * 32 + (l >> 4) * 8];
#pragma unroll
      for (int dn = 0; dn < 6; ++dn) {
        bf16x8 vb = *(const bf16x8*)&Vt[(dn * 16 + (l & 15)) * 88 + ks * 32 + (l >> 4) * 8];
        oacc[0][dn] = __builtin_amdgcn_mfma_f32_16x16x32_bf16(pa0, vb, oacc[0][dn], 0, 0, 0);
        oacc[1][dn] = __builtin_amdgcn_mfma_f32_16x16x32_bf16(pa1, vb, oacc[1][dn], 0, 0, 0);
      }
    }
  }

#pragma unroll
  for (int o = 1; o < 16; o <<= 1)
#pragma unroll
    for (int mg = 0; mg < 2; ++mg)
#pragma unroll
      for (int j = 0; j < 4; ++j)
        lrun[mg][j] += __shfl_xor(lrun[mg][j], o);

  const int b = bh >> 4, h = bh & 15;
#pragma unroll
  for (int mg = 0; mg < 2; ++mg) {
    float inv[4];
#pragma unroll
    for (int j = 0; j < 4; ++j) inv[j] = 1.f / lrun[mg][j];
    const int sqb = q0 + w * 32 + mg * 16 + (l >> 4) * 4;
#pragma unroll
    for (int dn = 0; dn < 6; ++dn) {
      const int d = dn * 16 + (l & 15);
      if (d >= 88) continue;
#pragma unroll
      for (int j = 0; j < 4; ++j) {
        const int sq = sqb + j;
        if (sq < 577)
          ctx[((size_t)(b * 577 + sq)) * 1408 + h * 88 + d] = (__bf16)(oacc[mg][dn][j] * inv[j]);
      }
    }
  }
}

extern "C" void kernel_launch(void* const* d_in, const int* in_sizes, int n_in,
                              void* d_out, int out_size, void* d_ws, size_t ws_size,
                              hipStream_t stream) {
  const float* hs    = (const float*)d_in[0];
  const float* freqs = (const float*)d_in[1];
  const float* wqkv  = (const float*)d_in[2];
  const float* bqkv  = (const float*)d_in[3];
  const float* wo    = (const float*)d_in[4];
  const float* bo    = (const float*)d_in[5];
  float* out = (float*)d_out;

  char* ws = (char*)d_ws;
  size_t off = 0;
  auto alloc = [&](size_t bytes) {
    void* p = ws + off;
    off += (bytes + 255) & ~(size_t)255;
    return p;
  };
  __bf16* x_bf    = (__bf16*)alloc((size_t)MROWS * K_ * 2);
  __bf16* ctx_bf  = x_bf;  // aliased: x dead after GEMM1
  __bf16* wqkv_bf = (__bf16*)alloc((size_t)N1 * K_ * 2);
  __bf16* wo_bf   = (__bf16*)alloc((size_t)D_ * K_ * 2);
  __bf16* q_bf    = (__bf16*)alloc((size_t)MROWS * D_ * 2);
  __bf16* k_bf    = (__bf16*)alloc((size_t)MROWS * D_ * 2);
  __bf16* v_bf    = (__bf16*)alloc((size_t)MROWS * D_ * 2);
  __bf16* vt_g    = (__bf16*)d_out;  // V^T scratch in d_out; GEMM2 overwrites later

  const int n0 = MROWS * K_ / 4, n1 = N1 * K_ / 4, n2 = D_ * K_ / 4;
  cast3_bf16_kernel<<<(n0 + n1 + n2 + 255) / 256, 256, 0, stream>>>(
      hs, x_bf, n0, wqkv, wqkv_bf, n1, wo, wo_bf, n2);

  gemm_qkv_rope<<<33 * 73, 256, 0, stream>>>(x_bf, wqkv_bf, bqkv, freqs, q_bf, k_bf, v_bf);

  transpose_v<<<dim3(256, 10), 256, 0, stream>>>(v_bf, vt_g);

  attn_kernel<<<dim3(256, 5), 256, 0, stream>>>(q_bf, k_bf, vt_g, ctx_bf);

  gemm_out_bias<<<11 * 73, 256, 0, stream>>>(ctx_bf, wo_bf, bo, out);
}